// Round 1
// baseline (1161.912 us; speedup 1.0000x reference)
//
#include <hip/hip_runtime.h>
#include <math.h>

#define BATCH 128
#define LFULL 4096
#define DMODEL 64
#define LN_EPS 1e-5f

// ---------------------------------------------------------------------------
// pe[d][l] for d in [0,64), l in [0,4096): sinusoidal positional embedding
// ---------------------------------------------------------------------------
__global__ void pe_kernel(float* __restrict__ pe) {
    int idx = blockIdx.x * 256 + threadIdx.x;   // 64*4096 = 262144 total
    int d = idx >> 12;
    int l = idx & 4095;
    int i2 = d & ~1;
    float dv = expf((float)i2 * -0.14391156831212787f);  // -ln(10000)/64
    float ang = (float)l * dv;
    pe[idx] = (d & 1) ? cosf(ang) : sinf(ang);
}

// ---------------------------------------------------------------------------
// Shared conv core: lane = out-channel, wave handles 8 consecutive out
// positions starting at j0 (local). tile rows are stride-68, 16B aligned.
// acc[jj] = bias + sum_{din,k} tile[din][2*(j0+jj)+k] * w[lane][din][k]
// ---------------------------------------------------------------------------
__device__ __forceinline__ void conv_core(const float (*tile)[68],
                                          const float4* __restrict__ cw4,
                                          float bias, int lane, int j0,
                                          float acc[8]) {
#pragma unroll
    for (int jj = 0; jj < 8; ++jj) acc[jj] = bias;
    for (int c = 0; c < 4; ++c) {
        float4 wr[16];
#pragma unroll
        for (int i = 0; i < 16; ++i) wr[i] = cw4[lane * 64 + c * 16 + i];
#pragma unroll
        for (int i = 0; i < 16; ++i) {
            int din = c * 16 + i;
            const float4* row = (const float4*)&tile[din][2 * j0];  // 2*j0 % 4 == 0
            float4 q0 = row[0], q1 = row[1], q2 = row[2], q3 = row[3], q4 = row[4];
            float v[20];
            v[0]=q0.x;  v[1]=q0.y;  v[2]=q0.z;  v[3]=q0.w;
            v[4]=q1.x;  v[5]=q1.y;  v[6]=q1.z;  v[7]=q1.w;
            v[8]=q2.x;  v[9]=q2.y;  v[10]=q2.z; v[11]=q2.w;
            v[12]=q3.x; v[13]=q3.y; v[14]=q3.z; v[15]=q3.w;
            v[16]=q4.x; v[17]=q4.y; v[18]=q4.z; v[19]=q4.w;
#pragma unroll
            for (int jj = 0; jj < 8; ++jj) {
                acc[jj] += v[2*jj]   * wr[i].x + v[2*jj+1] * wr[i].y
                         + v[2*jj+2] * wr[i].z + v[2*jj+3] * wr[i].w;
            }
        }
    }
}

// wave-64 LayerNorm over channels (lane = channel)
__device__ __forceinline__ float ln_apply(float t, float g, float bb) {
    float s = t;
#pragma unroll
    for (int m = 1; m < 64; m <<= 1) s += __shfl_xor(s, m, 64);
    float mean = s * 0.015625f;
    float df = t - mean;
    float q = df * df;
#pragma unroll
    for (int m = 1; m < 64; m <<= 1) q += __shfl_xor(q, m, 64);
    float var = q * 0.015625f;
    return df * rsqrtf(var + LN_EPS) * g + bb;
}

// ---------------------------------------------------------------------------
// Fused: token-embed (4 grouped convs, interleaved) + pos-embed  ->  LDS tile
//        -> stage-1 conv(k=4,s=2,p=1) -> tanh -> LN -> h1 (B,64,2048)
// Block: one batch b, 32 output positions. 256 threads = 4 waves.
// ---------------------------------------------------------------------------
__global__ __launch_bounds__(256, 3)
void emb_stage1_kernel(const float* __restrict__ x,
                       const float* __restrict__ w3, const float* __restrict__ b3,
                       const float* __restrict__ w5, const float* __restrict__ b5,
                       const float* __restrict__ w7, const float* __restrict__ b7,
                       const float* __restrict__ w9, const float* __restrict__ b9,
                       const float* __restrict__ cw, const float* __restrict__ cb,
                       const float* __restrict__ lng, const float* __restrict__ lnb,
                       const float* __restrict__ pe,
                       float* __restrict__ out) {
    const int b = blockIdx.y;
    const int l0 = blockIdx.x * 32;      // stage-1 output base
    const int pin0 = 2 * l0 - 1;         // h0 coordinate of tile column 0
    const int tid = threadIdx.x;

    __shared__ __align__(16) float tile[64][68];
    __shared__ float xs[80];
    __shared__ float ot[64][32];

    // x segment [pin0-4, pin0+69] (max token-conv halo = 4)
    if (tid < 74) {
        int g = pin0 - 4 + tid;
        xs[tid] = (g >= 0 && g < LFULL) ? x[b * LFULL + g] : 0.f;
    }
    __syncthreads();

    // h0 tile: token conv (kernel size by channel%4) + positional embedding
    for (int idx = tid; idx < 64 * 66; idx += 256) {
        int d = idx / 66;
        int p = idx - d * 66;
        int l = pin0 + p;
        float v = 0.f;
        if (l >= 0 && l < LFULL) {
            int ki = d & 3, g = d >> 2;
            int xb = p + 4;              // xs index of x[l]
            float a;
            if (ki == 0) {
                a = b3[g];
#pragma unroll
                for (int j = 0; j < 3; ++j) a += xs[xb + j - 1] * w3[g * 3 + j];
            } else if (ki == 1) {
                a = b5[g];
#pragma unroll
                for (int j = 0; j < 5; ++j) a += xs[xb + j - 2] * w5[g * 5 + j];
            } else if (ki == 2) {
                a = b7[g];
#pragma unroll
                for (int j = 0; j < 7; ++j) a += xs[xb + j - 3] * w7[g * 7 + j];
            } else {
                a = b9[g];
#pragma unroll
                for (int j = 0; j < 9; ++j) a += xs[xb + j - 4] * w9[g * 9 + j];
            }
            v = a + pe[(d << 12) + l];
        }
        tile[d][p] = v;
    }
    __syncthreads();

    const int lane = tid & 63;
    const int wv = tid >> 6;
    const int j0 = wv * 8;
    float acc[8];
    conv_core(tile, (const float4*)cw, cb[lane], lane, j0, acc);

    float g = lng[lane], bb = lnb[lane];
#pragma unroll
    for (int jj = 0; jj < 8; ++jj) {
        float t = tanhf(acc[jj]);
        ot[lane][j0 + jj] = ln_apply(t, g, bb);
    }
    __syncthreads();
    // coalesced (B,64,2048) store
    for (int idx = tid; idx < 64 * 32; idx += 256) {
        int d = idx >> 5;
        int p = idx & 31;
        out[(b * 64 + d) * 2048 + l0 + p] = ot[d][p];
    }
}

// ---------------------------------------------------------------------------
// Generic stage: conv(k=4,s=2,p=1) -> tanh -> [LN] ; input (B,64,LIN)
// DO_LN=true  -> output (B,64,LIN/2)
// DO_LN=false -> output transposed (B, LIN/2, 64)   [final stage]
// ---------------------------------------------------------------------------
template <int LIN, bool DO_LN>
__global__ __launch_bounds__(256, 3)
void stage_kernel(const float* __restrict__ in,
                  const float* __restrict__ cw, const float* __restrict__ cb,
                  const float* __restrict__ lng, const float* __restrict__ lnb,
                  float* __restrict__ out) {
    constexpr int LOUT = LIN / 2;
    const int b = blockIdx.y;
    const int l0 = blockIdx.x * 32;
    const int pin0 = 2 * l0 - 1;
    const int tid = threadIdx.x;

    __shared__ __align__(16) float tile[64][68];
    __shared__ float ot[64][32];

    for (int idx = tid; idx < 64 * 66; idx += 256) {
        int d = idx / 66;
        int p = idx - d * 66;
        int g = pin0 + p;
        tile[d][p] = (g >= 0 && g < LIN) ? in[(b * 64 + d) * LIN + g] : 0.f;
    }
    __syncthreads();

    const int lane = tid & 63;
    const int wv = tid >> 6;
    const int j0 = wv * 8;
    float acc[8];
    conv_core(tile, (const float4*)cw, cb[lane], lane, j0, acc);

    if (DO_LN) {
        float g = lng[lane], bb = lnb[lane];
#pragma unroll
        for (int jj = 0; jj < 8; ++jj) {
            float t = tanhf(acc[jj]);
            ot[lane][j0 + jj] = ln_apply(t, g, bb);
        }
        __syncthreads();
        for (int idx = tid; idx < 64 * 32; idx += 256) {
            int d = idx >> 5;
            int p = idx & 31;
            out[(b * 64 + d) * LOUT + l0 + p] = ot[d][p];
        }
    } else {
        // final stage: direct transposed store (B, LOUT, 64), coalesced in lane
#pragma unroll
        for (int jj = 0; jj < 8; ++jj) {
            out[(b * LOUT + l0 + j0 + jj) * 64 + lane] = tanhf(acc[jj]);
        }
    }
}

extern "C" void kernel_launch(void* const* d_in, const int* in_sizes, int n_in,
                              void* d_out, int out_size, void* d_ws, size_t ws_size,
                              hipStream_t stream) {
    (void)in_sizes; (void)n_in; (void)out_size; (void)ws_size;
    const float* x   = (const float*)d_in[0];
    const float* w3  = (const float*)d_in[1];
    const float* b3  = (const float*)d_in[2];
    const float* w5  = (const float*)d_in[3];
    const float* b5  = (const float*)d_in[4];
    const float* w7  = (const float*)d_in[5];
    const float* b7  = (const float*)d_in[6];
    const float* w9  = (const float*)d_in[7];
    const float* b9  = (const float*)d_in[8];
    const float* cw1 = (const float*)d_in[9];
    const float* cb1 = (const float*)d_in[10];
    const float* cw2 = (const float*)d_in[11];
    const float* cb2 = (const float*)d_in[12];
    const float* cw3 = (const float*)d_in[13];
    const float* cb3 = (const float*)d_in[14];
    const float* lg1 = (const float*)d_in[15];
    const float* lb1 = (const float*)d_in[16];
    const float* lg2 = (const float*)d_in[17];
    const float* lb2 = (const float*)d_in[18];
    float* out = (float*)d_out;

    // workspace layout (floats): pe 262144 | h1 16777216 | h2 8388608  (~97 MB)
    float* ws = (float*)d_ws;
    float* pe = ws;
    float* h1 = pe + 64 * 4096;
    float* h2 = h1 + BATCH * 64 * 2048;

    pe_kernel<<<1024, 256, 0, stream>>>(pe);
    emb_stage1_kernel<<<dim3(64, BATCH), 256, 0, stream>>>(
        x, w3, b3, w5, b5, w7, b7, w9, b9, cw1, cb1, lg1, lb1, pe, h1);
    stage_kernel<2048, true><<<dim3(32, BATCH), 256, 0, stream>>>(
        h1, cw2, cb2, lg2, lb2, h2);
    stage_kernel<1024, false><<<dim3(16, BATCH), 256, 0, stream>>>(
        h2, cw3, cb3, nullptr, nullptr, out);
}

// Round 2
// 601.280 us; speedup vs baseline: 1.9324x; 1.9324x over previous
//
#include <hip/hip_runtime.h>
#include <math.h>

#define BATCH 128
#define LFULL 4096
#define LN_EPS 1e-5f

// ---------------------------------------------------------------------------
// tanh via fast exp: exact at saturation (e=inf -> 1, e=0 -> -1)
// ---------------------------------------------------------------------------
__device__ __forceinline__ float fast_tanh(float v) {
    float e = __expf(2.f * v);
    return 1.f - 2.f / (e + 1.f);
}

// ---------------------------------------------------------------------------
// Transpose the three stage-conv weights (dout,din,k) -> (din,dout,k).
// idx layout: din = idx>>8, dout = (idx>>2)&63, k = idx&3.
// ---------------------------------------------------------------------------
__global__ void wtrans_kernel(const float* __restrict__ w1, const float* __restrict__ w2,
                              const float* __restrict__ w3f,
                              float* __restrict__ o1, float* __restrict__ o2,
                              float* __restrict__ o3) {
    int idx = blockIdx.x * 256 + threadIdx.x;   // 16384
    int k = idx & 3, dout = (idx >> 2) & 63, din = idx >> 8;
    int src = dout * 256 + din * 4 + k;
    o1[idx] = w1[src];
    o2[idx] = w2[src];
    o3[idx] = w3f[src];
}

// ---------------------------------------------------------------------------
// pe1c[dout][l] = cb1[dout] + conv1(pe_zeropad)[dout][l],  l in [0,2048)
// Batch-independent: computed once. Block = 64 output positions; 4 waves
// split dout into chunks of 16.
// ---------------------------------------------------------------------------
__global__ __launch_bounds__(256, 2)
void pe1_kernel(const float* __restrict__ wt1, const float* __restrict__ cb1,
                float* __restrict__ pe1c) {
    __shared__ float tile[64][132];
    const int tid = threadIdx.x;
    const int l0 = blockIdx.x * 64;
    const int pin0 = 2 * l0 - 1;
    for (int idx = tid; idx < 64 * 130; idx += 256) {
        int d = idx / 130, pp = idx - d * 130;
        int p = pin0 + pp;
        float v = 0.f;
        if (p >= 0 && p < LFULL) {
            float dv = expf((float)(d & ~1) * -0.14391156831212787f);  // -ln(1e4)/64
            float ang = (float)p * dv;
            v = (d & 1) ? cosf(ang) : sinf(ang);
        }
        tile[d][pp] = v;
    }
    __syncthreads();
    const int lane = tid & 63, wv = tid >> 6;
    const int l = l0 + lane, db = wv * 16;
    float acc[16];
#pragma unroll
    for (int j = 0; j < 16; ++j) acc[j] = cb1[db + j];
    for (int din = 0; din < 64; ++din) {
        float v0 = tile[din][2 * lane + 0], v1 = tile[din][2 * lane + 1];
        float v2 = tile[din][2 * lane + 2], v3 = tile[din][2 * lane + 3];
        const float* w = wt1 + din * 256 + db * 4;
#pragma unroll
        for (int j = 0; j < 16; ++j) {
            const float* wj = w + j * 4;
            acc[j] = fmaf(v0, wj[0], fmaf(v1, wj[1], fmaf(v2, wj[2], fmaf(v3, wj[3], acc[j]))));
        }
    }
#pragma unroll
    for (int j = 0; j < 16; ++j) pe1c[(db + j) * 2048 + l] = acc[j];
}

// ---------------------------------------------------------------------------
// Stage 1: token-embed (inline, lane-local) -> conv1(k=4,s=2,p=1) -> tanh ->
// LN -> h1 (B,64,2048).  lane = output position, acc[64] = all channels.
// pe contribution is pre-folded into pe1c (linear through conv1).
// ---------------------------------------------------------------------------
__global__ __launch_bounds__(256, 4)
void stage1_kernel(const float* __restrict__ x,
                   const float* __restrict__ w3, const float* __restrict__ b3,
                   const float* __restrict__ w5, const float* __restrict__ b5,
                   const float* __restrict__ w7, const float* __restrict__ b7,
                   const float* __restrict__ w9, const float* __restrict__ b9,
                   const float* __restrict__ wt1,   // (din,dout,k)
                   const float* __restrict__ pe1c,  // (dout,2048), includes cb1
                   const float* __restrict__ lng, const float* __restrict__ lnb,
                   float* __restrict__ out) {
    const int b = blockIdx.y;
    const int l = blockIdx.x * 256 + threadIdx.x;   // [0,2048)
    // x window for h0 positions p in {2l-1..2l+2} with halo 4: x[2l-5 .. 2l+6]
    float xv[12];
    const float* xb = x + b * LFULL;
    const int base = 2 * l - 5;
#pragma unroll
    for (int i = 0; i < 12; ++i) {
        int g = base + i;
        int gc = min(max(g, 0), LFULL - 1);
        float v = xb[gc];
        xv[i] = (g >= 0 && g < LFULL) ? v : 0.f;
    }
    float acc[64];
#pragma unroll
    for (int j = 0; j < 64; ++j) acc[j] = pe1c[j * 2048 + l];

    const bool pl = (l > 0), pr = (l < 2047);
    for (int din = 0; din < 64; ++din) {
        const int ki = din & 3, g = din >> 2;
        float t[4];
        if (ki == 0) {
            const float* w = w3 + g * 3; float bb = b3[g];
#pragma unroll
            for (int m = 0; m < 4; ++m) { float a = bb;
#pragma unroll
                for (int j = 0; j < 3; ++j) a = fmaf(xv[m + 3 + j], w[j], a);
                t[m] = a; }
        } else if (ki == 1) {
            const float* w = w5 + g * 5; float bb = b5[g];
#pragma unroll
            for (int m = 0; m < 4; ++m) { float a = bb;
#pragma unroll
                for (int j = 0; j < 5; ++j) a = fmaf(xv[m + 2 + j], w[j], a);
                t[m] = a; }
        } else if (ki == 2) {
            const float* w = w7 + g * 7; float bb = b7[g];
#pragma unroll
            for (int m = 0; m < 4; ++m) { float a = bb;
#pragma unroll
                for (int j = 0; j < 7; ++j) a = fmaf(xv[m + 1 + j], w[j], a);
                t[m] = a; }
        } else {
            const float* w = w9 + g * 9; float bb = b9[g];
#pragma unroll
            for (int m = 0; m < 4; ++m) { float a = bb;
#pragma unroll
                for (int j = 0; j < 9; ++j) a = fmaf(xv[m + j], w[j], a);
                t[m] = a; }
        }
        if (!pl) t[0] = 0.f;   // conv1 left zero-pad (p = -1)
        if (!pr) t[3] = 0.f;   // conv1 right zero-pad (p = 4096)
        const float* w = wt1 + din * 256;
#pragma unroll
        for (int j = 0; j < 64; ++j) {
            const float* wj = w + j * 4;
            acc[j] = fmaf(t[0], wj[0], fmaf(t[1], wj[1], fmaf(t[2], wj[2], fmaf(t[3], wj[3], acc[j]))));
        }
    }
    // tanh -> LN over channels (all in-lane)
    float s = 0.f;
#pragma unroll
    for (int j = 0; j < 64; ++j) { acc[j] = fast_tanh(acc[j]); s += acc[j]; }
    float mean = s * 0.015625f;
    float q = 0.f;
#pragma unroll
    for (int j = 0; j < 64; ++j) { float d = acc[j] - mean; q = fmaf(d, d, q); }
    float rstd = rsqrtf(q * 0.015625f + LN_EPS);
    float* ob = out + (size_t)(b * 64) * 2048 + l;
#pragma unroll
    for (int j = 0; j < 64; ++j)
        ob[(size_t)j * 2048] = (acc[j] - mean) * rstd * lng[j] + lnb[j];
}

// ---------------------------------------------------------------------------
// Stages 2/3: conv(k=4,s=2,p=1) -> tanh -> [LN].  lane = output position.
// DO_LN=true  -> out (B,64,LOUT);  false -> transposed (B,LOUT,64) float4 x16.
// ---------------------------------------------------------------------------
template <int LIN, bool DO_LN>
__global__ __launch_bounds__(256, 4)
void stage_kernel(const float* __restrict__ in, const float* __restrict__ wt,
                  const float* __restrict__ cb,
                  const float* __restrict__ lng, const float* __restrict__ lnb,
                  float* __restrict__ out) {
    constexpr int LOUT = LIN / 2;
    const int b = blockIdx.y;
    const int l = blockIdx.x * 256 + threadIdx.x;   // [0,LOUT)
    const float* inb = in + (size_t)(b * 64) * LIN + 2 * l - 1;
    const bool pl = (l > 0), pr = (l < LOUT - 1);
    const int i0 = pl ? 0 : 1;       // clamp addresses; value predicated below
    const int i3 = pr ? 3 : 2;
    float acc[64];
#pragma unroll
    for (int j = 0; j < 64; ++j) acc[j] = cb[j];
    for (int din = 0; din < 64; ++din) {
        const float* r = inb + (size_t)din * LIN;
        float v0 = r[i0]; v0 = pl ? v0 : 0.f;
        float v1 = r[1];
        float v2 = r[2];
        float v3 = r[i3]; v3 = pr ? v3 : 0.f;
        const float* w = wt + din * 256;
#pragma unroll
        for (int j = 0; j < 64; ++j) {
            const float* wj = w + j * 4;
            acc[j] = fmaf(v0, wj[0], fmaf(v1, wj[1], fmaf(v2, wj[2], fmaf(v3, wj[3], acc[j]))));
        }
    }
    if (DO_LN) {
        float s = 0.f;
#pragma unroll
        for (int j = 0; j < 64; ++j) { acc[j] = fast_tanh(acc[j]); s += acc[j]; }
        float mean = s * 0.015625f;
        float q = 0.f;
#pragma unroll
        for (int j = 0; j < 64; ++j) { float d = acc[j] - mean; q = fmaf(d, d, q); }
        float rstd = rsqrtf(q * 0.015625f + LN_EPS);
        float* ob = out + (size_t)(b * 64) * LOUT + l;
#pragma unroll
        for (int j = 0; j < 64; ++j)
            ob[(size_t)j * LOUT] = (acc[j] - mean) * rstd * lng[j] + lnb[j];
    } else {
#pragma unroll
        for (int j = 0; j < 64; ++j) acc[j] = fast_tanh(acc[j]);
        float4* op = (float4*)(out + (size_t)(b * LOUT + l) * 64);
#pragma unroll
        for (int j = 0; j < 16; ++j)
            op[j] = make_float4(acc[4 * j], acc[4 * j + 1], acc[4 * j + 2], acc[4 * j + 3]);
    }
}

extern "C" void kernel_launch(void* const* d_in, const int* in_sizes, int n_in,
                              void* d_out, int out_size, void* d_ws, size_t ws_size,
                              hipStream_t stream) {
    (void)in_sizes; (void)n_in; (void)out_size; (void)ws_size;
    const float* x   = (const float*)d_in[0];
    const float* w3  = (const float*)d_in[1];
    const float* b3  = (const float*)d_in[2];
    const float* w5  = (const float*)d_in[3];
    const float* b5  = (const float*)d_in[4];
    const float* w7  = (const float*)d_in[5];
    const float* b7  = (const float*)d_in[6];
    const float* w9  = (const float*)d_in[7];
    const float* b9  = (const float*)d_in[8];
    const float* cw1 = (const float*)d_in[9];
    const float* cb1 = (const float*)d_in[10];
    const float* cw2 = (const float*)d_in[11];
    const float* cb2 = (const float*)d_in[12];
    const float* cw3 = (const float*)d_in[13];
    const float* cb3 = (const float*)d_in[14];
    const float* lg1 = (const float*)d_in[15];
    const float* lb1 = (const float*)d_in[16];
    const float* lg2 = (const float*)d_in[17];
    const float* lb2 = (const float*)d_in[18];
    float* out = (float*)d_out;

    // ws (floats): wt1 16K | wt2 16K | wt3 16K | pe1c 128K | h1 16M | h2 8M  (~101 MB)
    float* ws = (float*)d_ws;
    float* wt1  = ws;
    float* wt2  = wt1 + 64 * 64 * 4;
    float* wt3  = wt2 + 64 * 64 * 4;
    float* pe1c = wt3 + 64 * 64 * 4;
    float* h1   = pe1c + 64 * 2048;
    float* h2   = h1 + (size_t)BATCH * 64 * 2048;

    wtrans_kernel<<<64, 256, 0, stream>>>(cw1, cw2, cw3, wt1, wt2, wt3);
    pe1_kernel<<<32, 256, 0, stream>>>(wt1, cb1, pe1c);
    stage1_kernel<<<dim3(8, BATCH), 256, 0, stream>>>(
        x, w3, b3, w5, b5, w7, b7, w9, b9, wt1, pe1c, lg1, lb1, h1);
    stage_kernel<2048, true><<<dim3(4, BATCH), 256, 0, stream>>>(
        h1, wt2, cb2, lg2, lb2, h2);
    stage_kernel<1024, false><<<dim3(2, BATCH), 256, 0, stream>>>(
        h2, wt3, cb3, nullptr, nullptr, out);
}

// Round 3
// 305.093 us; speedup vs baseline: 3.8084x; 1.9708x over previous
//
#include <hip/hip_runtime.h>
#include <math.h>

#define BATCH 128
#define LN_EPS 1e-5f

typedef short bf16x8 __attribute__((ext_vector_type(8)));
typedef float f32x4  __attribute__((ext_vector_type(4)));

__device__ __forceinline__ ushort f2bf(float f) {
    union { float f; unsigned u; } c; c.f = f;
    unsigned r = c.u + 0x7FFF + ((c.u >> 16) & 1);   // round-nearest-even
    return (ushort)(r >> 16);
}

__device__ __forceinline__ float fast_tanh(float v) {
    float e = __expf(2.f * v);
    return 1.f - 2.f / (e + 1.f);
}

// ---------------------------------------------------------------------------
// prep: (a) Wm[s]: stage-s conv weights (dout,256) -> bf16 MFMA A-fragment
//           layout: Wm[s][((k>>3)*64 + dout)*8 + (k&7)]
//       (b) w9p[64][9]: token-conv weights zero-padded to a uniform 9-tap
//           window centered at offset 4; tb[64]: token-conv biases.
// ---------------------------------------------------------------------------
__global__ void prep_kernel(const float* __restrict__ cw1, const float* __restrict__ cw2,
                            const float* __restrict__ cw3,
                            const float* __restrict__ w3, const float* __restrict__ b3,
                            const float* __restrict__ w5, const float* __restrict__ b5,
                            const float* __restrict__ w7, const float* __restrict__ b7,
                            const float* __restrict__ w9, const float* __restrict__ b9,
                            ushort* __restrict__ Wm, float* __restrict__ w9p,
                            float* __restrict__ tb) {
    int idx = blockIdx.x * 256 + threadIdx.x;      // grid covers 3*16384
    if (idx < 3 * 16384) {
        int s = idx >> 14, r = idx & 16383;
        int dout = r >> 8, k = r & 255;
        const float* cw = (s == 0) ? cw1 : (s == 1) ? cw2 : cw3;
        Wm[s * 16384 + ((k >> 3) * 64 + dout) * 8 + (k & 7)] = f2bf(cw[dout * 256 + k]);
    }
    if (idx < 64) {
        int din = idx, ki = din & 3, g = din >> 2;
        float wl[9];
#pragma unroll
        for (int j = 0; j < 9; ++j) wl[j] = 0.f;
        float bias;
        if (ki == 0)      { for (int j = 0; j < 3; ++j) wl[3 + j] = w3[g * 3 + j]; bias = b3[g]; }
        else if (ki == 1) { for (int j = 0; j < 5; ++j) wl[2 + j] = w5[g * 5 + j]; bias = b5[g]; }
        else if (ki == 2) { for (int j = 0; j < 7; ++j) wl[1 + j] = w7[g * 7 + j]; bias = b7[g]; }
        else              { for (int j = 0; j < 9; ++j) wl[j]     = w9[g * 9 + j]; bias = b9[g]; }
        for (int j = 0; j < 9; ++j) w9p[din * 9 + j] = wl[j];
        tb[din] = bias;
    }
}

// ---------------------------------------------------------------------------
// pe1c[dout][l] = cb1[dout] + conv1(pe)[dout][l] (fp32, batch-independent)
// ---------------------------------------------------------------------------
__global__ __launch_bounds__(256, 2)
void pe1_kernel(const float* __restrict__ cw1, const float* __restrict__ cb1,
                float* __restrict__ pe1c) {
    __shared__ float tile[64][132];
    const int tid = threadIdx.x;
    const int l0 = blockIdx.x * 64;
    const int pin0 = 2 * l0 - 1;
    for (int idx = tid; idx < 64 * 130; idx += 256) {
        int d = idx / 130, pp = idx - d * 130;
        int p = pin0 + pp;
        float v = 0.f;
        if (p >= 0 && p < 4096) {
            float dv = expf((float)(d & ~1) * -0.14391156831212787f);  // -ln(1e4)/64
            float ang = (float)p * dv;
            v = (d & 1) ? cosf(ang) : sinf(ang);
        }
        tile[d][pp] = v;
    }
    __syncthreads();
    const int lane = tid & 63, wv = tid >> 6;
    const int l = l0 + lane, db = wv * 16;
    float acc[16];
#pragma unroll
    for (int j = 0; j < 16; ++j) acc[j] = cb1[db + j];
    for (int din = 0; din < 64; ++din) {
        float v0 = tile[din][2 * lane + 0], v1 = tile[din][2 * lane + 1];
        float v2 = tile[din][2 * lane + 2], v3 = tile[din][2 * lane + 3];
        const float* wb = cw1 + din * 4;
#pragma unroll
        for (int j = 0; j < 16; ++j) {
            const float* wj = wb + (db + j) * 256;
            acc[j] = fmaf(v0, wj[0], fmaf(v1, wj[1], fmaf(v2, wj[2], fmaf(v3, wj[3], acc[j]))));
        }
    }
#pragma unroll
    for (int j = 0; j < 16; ++j) pe1c[(db + j) * 2048 + l] = acc[j];
}

// ---------------------------------------------------------------------------
// MFMA stage: conv(k=4,s=2,p=1) as GEMM C[dout][pos] = W(64x256) @ P(256x128)
// Block: 128 positions x 64 douts, 4 waves (wave = 32 pos x 64 douts).
// P staged in LDS in B-fragment layout; W frags loaded from global (L1-hot).
// STAGE==1: input = token-conv of x (computed inline); +pe1c in epilogue.
// STAGE<3: tanh+LN, store bf16 (B,64,LOUT). STAGE==3: tanh, fp32 (B,512,64).
// ---------------------------------------------------------------------------
template <int STAGE>
__global__ __launch_bounds__(256, 2)
void stage_mfma(const float* __restrict__ x, const ushort* __restrict__ hin,
                const ushort* __restrict__ Wg,
                const float* __restrict__ w9p, const float* __restrict__ tb,
                const float* __restrict__ pe1c, const float* __restrict__ cb,
                const float* __restrict__ lng, const float* __restrict__ lnb,
                ushort* __restrict__ hout, float* __restrict__ out) {
    constexpr int LIN  = (STAGE == 1) ? 4096 : (STAGE == 2) ? 2048 : 1024;
    constexpr int LOUT = LIN / 2;
    const int b = blockIdx.y;
    const int l0 = blockIdx.x * 128;
    const int tid = threadIdx.x;
    const int p0 = 2 * l0 - 1;

    __shared__ __align__(16) ushort P[32768];   // [(k>>3)*128 + m]*8 + (k&7)
    __shared__ float xs[272];

    if (STAGE == 1) {
        // x window [p0-4, p0+261]
        for (int i = tid; i < 266; i += 256) {
            int g = p0 - 4 + i;
            xs[i] = (g >= 0 && g < 4096) ? x[b * 4096 + g] : 0.f;
        }
        __syncthreads();
        const int din = tid & 63;
        float w[9];
#pragma unroll
        for (int j = 0; j < 9; ++j) w[j] = w9p[din * 9 + j];
        const float bias = tb[din];
        const int kbase = din * 4;
        for (int pp = tid >> 6; pp < 258; pp += 4) {
            int p = p0 + pp;
            float v = 0.f;
            if (p >= 0 && p < 4096) {
                v = bias;
#pragma unroll
                for (int j = 0; j < 9; ++j) v = fmaf(xs[pp + j], w[j], v);
            }
            ushort bv = f2bf(v);
            int par = (p + 1) & 1;
#pragma unroll
            for (int t = 0; t < 2; ++t) {
                int kk = par + 2 * t;
                int m = ((p + 1 - kk) >> 1) - l0;
                if (m >= 0 && m < 128) {
                    int k = kbase + kk;
                    P[((k >> 3) * 128 + m) * 8 + (k & 7)] = bv;
                }
            }
        }
    } else {
        const int din = tid & 63;
        const ushort* row = hin + ((size_t)(b * 64 + din)) * LIN;
        const int kbase = din * 4;
        const int p0e = p0 - 1;                 // even
        for (int c = tid >> 6; c < 33; c += 4) {
            int pbase = p0e + c * 8;
            ushort hv[8];
#pragma unroll
            for (int q = 0; q < 4; ++q) {
                int pi = pbase + 2 * q;
                unsigned u = 0;
                if (pi >= 0 && pi < LIN) u = *(const unsigned*)(row + pi);
                hv[2 * q] = (ushort)u;
                hv[2 * q + 1] = (ushort)(u >> 16);
            }
#pragma unroll
            for (int j = 0; j < 8; ++j) {
                int p = pbase + j;
                int par = (p + 1) & 1;
#pragma unroll
                for (int t = 0; t < 2; ++t) {
                    int kk = par + 2 * t;
                    int m = ((p + 1 - kk) >> 1) - l0;
                    if (m >= 0 && m < 128) {
                        int k = kbase + kk;
                        P[((k >> 3) * 128 + m) * 8 + (k & 7)] = hv[j];
                    }
                }
            }
        }
    }
    __syncthreads();

    const int wv = tid >> 6;          // wave: positions wv*32 .. wv*32+31
    const int lane = tid & 63;
    const int quad = lane >> 4, l15 = lane & 15;

    f32x4 acc[2][4];
#pragma unroll
    for (int pt = 0; pt < 2; ++pt)
#pragma unroll
        for (int dt = 0; dt < 4; ++dt) acc[pt][dt] = (f32x4)0.f;

#pragma unroll
    for (int s = 0; s < 8; ++s) {
        bf16x8 bfr[2], afr[4];
#pragma unroll
        for (int pt = 0; pt < 2; ++pt)
            bfr[pt] = *(const bf16x8*)&P[((s * 4 + quad) * 128 + wv * 32 + pt * 16 + l15) * 8];
#pragma unroll
        for (int dt = 0; dt < 4; ++dt)
            afr[dt] = *(const bf16x8*)&Wg[((s * 4 + quad) * 64 + dt * 16 + l15) * 8];
#pragma unroll
        for (int pt = 0; pt < 2; ++pt)
#pragma unroll
            for (int dt = 0; dt < 4; ++dt)
                acc[pt][dt] = __builtin_amdgcn_mfma_f32_16x16x32_bf16(
                    afr[dt], bfr[pt], acc[pt][dt], 0, 0, 0);
    }

    // epilogue: lane holds pos = l0+wv*32+pt*16+l15, channels ch = dt*16+quad*4+r
#pragma unroll
    for (int pt = 0; pt < 2; ++pt) {
        const int l = l0 + wv * 32 + pt * 16 + l15;
        float v[16];
#pragma unroll
        for (int dt = 0; dt < 4; ++dt)
#pragma unroll
            for (int r = 0; r < 4; ++r) {
                int ch = dt * 16 + quad * 4 + r;
                float a = acc[pt][dt][r];
                a += (STAGE == 1) ? pe1c[ch * 2048 + l] : cb[ch];
                v[dt * 4 + r] = fast_tanh(a);
            }
        if (STAGE < 3) {
            float s = 0.f;
#pragma unroll
            for (int i = 0; i < 16; ++i) s += v[i];
            s += __shfl_xor(s, 16, 64);
            s += __shfl_xor(s, 32, 64);
            float mean = s * 0.015625f;
            float q = 0.f;
#pragma unroll
            for (int i = 0; i < 16; ++i) { float d = v[i] - mean; q = fmaf(d, d, q); }
            q += __shfl_xor(q, 16, 64);
            q += __shfl_xor(q, 32, 64);
            float rstd = rsqrtf(q * 0.015625f + LN_EPS);
#pragma unroll
            for (int dt = 0; dt < 4; ++dt)
#pragma unroll
                for (int r = 0; r < 4; ++r) {
                    int ch = dt * 16 + quad * 4 + r;
                    float val = (v[dt * 4 + r] - mean) * rstd * lng[ch] + lnb[ch];
                    hout[((size_t)(b * 64 + ch)) * LOUT + l] = f2bf(val);
                }
        } else {
            float* ob = out + ((size_t)(b * 512) + l) * 64;
#pragma unroll
            for (int dt = 0; dt < 4; ++dt) {
                float4 st = make_float4(v[dt * 4], v[dt * 4 + 1], v[dt * 4 + 2], v[dt * 4 + 3]);
                *(float4*)(ob + dt * 16 + quad * 4) = st;
            }
        }
    }
}

extern "C" void kernel_launch(void* const* d_in, const int* in_sizes, int n_in,
                              void* d_out, int out_size, void* d_ws, size_t ws_size,
                              hipStream_t stream) {
    (void)in_sizes; (void)n_in; (void)out_size; (void)ws_size;
    const float* x   = (const float*)d_in[0];
    const float* w3  = (const float*)d_in[1];
    const float* b3  = (const float*)d_in[2];
    const float* w5  = (const float*)d_in[3];
    const float* b5  = (const float*)d_in[4];
    const float* w7  = (const float*)d_in[5];
    const float* b7  = (const float*)d_in[6];
    const float* w9  = (const float*)d_in[7];
    const float* b9  = (const float*)d_in[8];
    const float* cw1 = (const float*)d_in[9];
    const float* cb1 = (const float*)d_in[10];
    const float* cw2 = (const float*)d_in[11];
    const float* cb2 = (const float*)d_in[12];
    const float* cw3 = (const float*)d_in[13];
    const float* cb3 = (const float*)d_in[14];
    const float* lg1 = (const float*)d_in[15];
    const float* lb1 = (const float*)d_in[16];
    const float* lg2 = (const float*)d_in[17];
    const float* lb2 = (const float*)d_in[18];
    float* out = (float*)d_out;

    // ws layout (bytes):
    char* w = (char*)d_ws;
    ushort* Wm   = (ushort*)(w + 0);          //  98304 B (3 x 16384 bf16)
    float*  w9p  = (float*)(w + 98304);       //   2304 B
    float*  tb   = (float*)(w + 100608);      //    256 B
    float*  pe1c = (float*)(w + 100864);      // 524288 B
    ushort* h1   = (ushort*)(w + 625152);     // 33554432 B (128,64,2048) bf16
    ushort* h2   = (ushort*)(w + 34179584);   // 16777216 B (128,64,1024) bf16

    prep_kernel<<<192, 256, 0, stream>>>(cw1, cw2, cw3, w3, b3, w5, b5, w7, b7, w9, b9,
                                         Wm, w9p, tb);
    pe1_kernel<<<32, 256, 0, stream>>>(cw1, cb1, pe1c);

    stage_mfma<1><<<dim3(16, BATCH), 256, 0, stream>>>(
        x, nullptr, Wm, w9p, tb, pe1c, nullptr, lg1, lb1, h1, nullptr);
    stage_mfma<2><<<dim3(8, BATCH), 256, 0, stream>>>(
        nullptr, h1, Wm + 16384, nullptr, nullptr, nullptr, cb2, lg2, lb2, h2, nullptr);
    stage_mfma<3><<<dim3(4, BATCH), 256, 0, stream>>>(
        nullptr, h2, Wm + 32768, nullptr, nullptr, nullptr, cb3, nullptr, nullptr, nullptr, out);
}

// Round 5
// 208.339 us; speedup vs baseline: 5.5770x; 1.4644x over previous
//
#include <hip/hip_runtime.h>
#include <math.h>

#define BATCH 128
#define LN_EPS 1e-5f

typedef short bf16x8 __attribute__((ext_vector_type(8)));
typedef short bf16x4 __attribute__((ext_vector_type(4)));
typedef float f32x4  __attribute__((ext_vector_type(4)));

__device__ __forceinline__ ushort f2bf(float f) {
    union { float f; unsigned u; } c; c.f = f;
    unsigned r = c.u + 0x7FFF + ((c.u >> 16) & 1);   // round-nearest-even
    return (ushort)(r >> 16);
}

__device__ __forceinline__ float fast_tanh(float v) {
    float e = __expf(2.f * v);
    return 1.f - 2.f / (e + 1.f);
}

// ---------------------------------------------------------------------------
// prep: (a) Wm[s]: stage-s conv weights -> bf16 A-fragment layout for the
//     tap-split GEMM:  flat index bits  kk[13:12] k2[11] quad[10:9] dt[8:7]
//     l15[6:3] j[2:0]  <->  dout = dt*16+l15, din = k2*32+quad*8+j, tap kk.
//       (b) w9p[64][9]: token-conv weights zero-padded to 9 taps; tb: biases.
// ---------------------------------------------------------------------------
__global__ void prep_kernel(const float* __restrict__ cw1, const float* __restrict__ cw2,
                            const float* __restrict__ cw3,
                            const float* __restrict__ w3, const float* __restrict__ b3,
                            const float* __restrict__ w5, const float* __restrict__ b5,
                            const float* __restrict__ w7, const float* __restrict__ b7,
                            const float* __restrict__ w9, const float* __restrict__ b9,
                            ushort* __restrict__ Wm, float* __restrict__ w9p,
                            float* __restrict__ tb) {
    int idx = blockIdx.x * 256 + threadIdx.x;      // 3*16384
    if (idx < 3 * 16384) {
        int s = idx >> 14, r = idx & 16383;
        int j = r & 7, l15 = (r >> 3) & 15, dt = (r >> 7) & 3;
        int quad = (r >> 9) & 3, k2 = (r >> 11) & 1, kk = (r >> 12) & 3;
        int dout = dt * 16 + l15, din = k2 * 32 + quad * 8 + j;
        const float* cw = (s == 0) ? cw1 : (s == 1) ? cw2 : cw3;
        Wm[idx] = f2bf(cw[dout * 256 + din * 4 + kk]);
    }
    if (idx < 64) {
        int din = idx, ki = din & 3, g = din >> 2;
        float wl[9];
#pragma unroll
        for (int j = 0; j < 9; ++j) wl[j] = 0.f;
        float bias;
        if (ki == 0)      { for (int j = 0; j < 3; ++j) wl[3 + j] = w3[g * 3 + j]; bias = b3[g]; }
        else if (ki == 1) { for (int j = 0; j < 5; ++j) wl[2 + j] = w5[g * 5 + j]; bias = b5[g]; }
        else if (ki == 2) { for (int j = 0; j < 7; ++j) wl[1 + j] = w7[g * 7 + j]; bias = b7[g]; }
        else              { for (int j = 0; j < 9; ++j) wl[j]     = w9[g * 9 + j]; bias = b9[g]; }
        for (int j = 0; j < 9; ++j) w9p[din * 9 + j] = wl[j];
        tb[din] = bias;
    }
}

// ---------------------------------------------------------------------------
// pe1c[l][dout] = cb1[dout] + conv1(pe)[dout][l]  (fp32, batch-independent)
// ---------------------------------------------------------------------------
__global__ __launch_bounds__(256, 2)
void pe1_kernel(const float* __restrict__ cw1, const float* __restrict__ cb1,
                float* __restrict__ pe1c) {
    __shared__ float tile[64][132];
    const int tid = threadIdx.x;
    const int l0 = blockIdx.x * 64;
    const int pin0 = 2 * l0 - 1;
    for (int idx = tid; idx < 64 * 130; idx += 256) {
        int d = idx / 130, pp = idx - d * 130;
        int p = pin0 + pp;
        float v = 0.f;
        if (p >= 0 && p < 4096) {
            float dv = expf((float)(d & ~1) * -0.14391156831212787f);  // -ln(1e4)/64
            float ang = (float)p * dv;
            v = (d & 1) ? cosf(ang) : sinf(ang);
        }
        tile[d][pp] = v;
    }
    __syncthreads();
    const int lane = tid & 63, wv = tid >> 6;
    const int l = l0 + lane, db = wv * 16;
    float acc[16];
#pragma unroll
    for (int j = 0; j < 16; ++j) acc[j] = cb1[db + j];
    for (int din = 0; din < 64; ++din) {
        float v0 = tile[din][2 * lane + 0], v1 = tile[din][2 * lane + 1];
        float v2 = tile[din][2 * lane + 2], v3 = tile[din][2 * lane + 3];
        const float* wb = cw1 + din * 4;
#pragma unroll
        for (int j = 0; j < 16; ++j) {
            const float* wj = wb + (db + j) * 256;
            acc[j] = fmaf(v0, wj[0], fmaf(v1, wj[1], fmaf(v2, wj[2], fmaf(v3, wj[3], acc[j]))));
        }
    }
#pragma unroll
    for (int j = 0; j < 16; ++j) pe1c[(size_t)l * 64 + db + j] = acc[j];
}

// ---------------------------------------------------------------------------
// Tap-split MFMA stage: conv(k=4,s=2,p=1) as 4 GEMMs of K=64.
// Parity tiles TE/TO hold input positions 2*l0+t: even t -> TE[t/2],
// odd t -> TO[(t+1)/2], t in [-1,256]; rows padded to 72 shorts (144 B,
// 16B-aligned, 2-way bank alias = free).
// Tap kk reads tile (kk&1 ? TE : TO) row m + (kk>>1).
// STAGE==1: input = token conv of x (inline, pos-major write, conflict-free);
//           epilogue adds pe1c. STAGE<3: tanh+LN -> bf16 (B,LOUT,64) via LDS.
// STAGE==3: tanh -> fp32 (B,512,64) direct.
// ---------------------------------------------------------------------------
template <int STAGE>
__global__ __launch_bounds__(256, 4)
void stage_mfma(const float* __restrict__ x, const ushort* __restrict__ hin,
                const ushort* __restrict__ Wg,
                const float* __restrict__ w9p, const float* __restrict__ tb,
                const float* __restrict__ pe1c, const float* __restrict__ cb,
                const float* __restrict__ lng, const float* __restrict__ lnb,
                ushort* __restrict__ hout, float* __restrict__ out) {
    constexpr int LIN  = (STAGE == 1) ? 4096 : (STAGE == 2) ? 2048 : 1024;
    constexpr int LOUT = LIN / 2;
    const int b = blockIdx.y;
    const int l0 = blockIdx.x * 128;
    const int tid = threadIdx.x;

    __shared__ __align__(16) ushort TE[129][72];
    __shared__ __align__(16) ushort TO[129][72];
    __shared__ float xs[272];

    if constexpr (STAGE == 1) {
        for (int i = tid; i < 266; i += 256) {
            int g = 2 * l0 - 5 + i;
            xs[i] = (g >= 0 && g < 4096) ? x[b * 4096 + g] : 0.f;
        }
        __syncthreads();
        const int din = tid & 63;
        float w[9];
#pragma unroll
        for (int j = 0; j < 9; ++j) w[j] = w9p[din * 9 + j];
        const float bias = tb[din];
        for (int t = -1 + (int)(tid >> 6); t <= 256; t += 4) {
            int pos = 2 * l0 + t;
            float v = 0.f;
            if (pos >= 0 && pos < 4096) {
                v = bias;
#pragma unroll
                for (int j = 0; j < 9; ++j) v = fmaf(xs[t + 1 + j], w[j], v);
            }
            ushort bv = f2bf(v);
            if (t & 1) TO[(t + 1) >> 1][din] = bv;
            else       TE[t >> 1][din] = bv;
        }
    } else {
        (void)x; (void)w9p; (void)tb;
        for (int idx = tid; idx < 258 * 8; idx += 256) {
            int row = idx >> 3, chb = (idx & 7) * 8;
            int pos = (row < 129) ? (2 * l0 + 2 * row) : (2 * l0 - 1 + 2 * (row - 129));
            bf16x8 val;
#pragma unroll
            for (int q = 0; q < 8; ++q) val[q] = 0;
            if (pos >= 0 && pos < LIN)
                val = *(const bf16x8*)(hin + ((size_t)b * LIN + pos) * 64 + chb);
            ushort* dst = (row < 129) ? &TE[row][chb] : &TO[row - 129][chb];
            *(bf16x8*)dst = val;
        }
    }
    __syncthreads();

    const int wv = tid >> 6, lane = tid & 63;
    const int quad = lane >> 4, l15 = lane & 15;
    const int m0 = wv * 32;                 // local output positions m0..m0+31

    f32x4 acc[2][4];
#pragma unroll
    for (int pt = 0; pt < 2; ++pt)
#pragma unroll
        for (int dt = 0; dt < 4; ++dt) acc[pt][dt] = (f32x4)0.f;

#pragma unroll
    for (int kk = 0; kk < 4; ++kk) {
        const ushort (*T)[72] = (kk & 1) ? TE : TO;
        const int dl = kk >> 1;
#pragma unroll
        for (int k2 = 0; k2 < 2; ++k2) {
            bf16x8 afr[4], bfr[2];
            const ushort* wb = Wg + ((((kk * 2 + k2) * 4 + quad) * 4) * 16) * 8;
#pragma unroll
            for (int dt = 0; dt < 4; ++dt)
                afr[dt] = *(const bf16x8*)(wb + ((size_t)(dt * 16 + l15)) * 8);
#pragma unroll
            for (int pt = 0; pt < 2; ++pt)
                bfr[pt] = *(const bf16x8*)&T[m0 + pt * 16 + l15 + dl][k2 * 32 + quad * 8];
#pragma unroll
            for (int pt = 0; pt < 2; ++pt)
#pragma unroll
                for (int dt = 0; dt < 4; ++dt)
                    acc[pt][dt] = __builtin_amdgcn_mfma_f32_16x16x32_bf16(
                        afr[dt], bfr[pt], acc[pt][dt], 0, 0, 0);
        }
    }

    // ---- epilogue: lane holds pos = l0+m0+pt*16+l15, ch = dt*16+quad*4+r ----
    if constexpr (STAGE < 3) {
        float vln[2][16];
#pragma unroll
        for (int pt = 0; pt < 2; ++pt) {
            const int l = l0 + m0 + pt * 16 + l15;
            float v[16];
            if constexpr (STAGE == 1) {
                const float* pb = pe1c + (size_t)l * 64;
#pragma unroll
                for (int dt = 0; dt < 4; ++dt) {
                    float4 pv = *(const float4*)(pb + dt * 16 + quad * 4);
                    v[dt * 4 + 0] = fast_tanh(acc[pt][dt][0] + pv.x);
                    v[dt * 4 + 1] = fast_tanh(acc[pt][dt][1] + pv.y);
                    v[dt * 4 + 2] = fast_tanh(acc[pt][dt][2] + pv.z);
                    v[dt * 4 + 3] = fast_tanh(acc[pt][dt][3] + pv.w);
                }
            } else {
#pragma unroll
                for (int dt = 0; dt < 4; ++dt)
#pragma unroll
                    for (int r = 0; r < 4; ++r)
                        v[dt * 4 + r] = fast_tanh(acc[pt][dt][r] + cb[dt * 16 + quad * 4 + r]);
            }
            float s = 0.f;
#pragma unroll
            for (int i = 0; i < 16; ++i) s += v[i];
            s += __shfl_xor(s, 16, 64);
            s += __shfl_xor(s, 32, 64);
            float mean = s * 0.015625f;
            float q = 0.f;
#pragma unroll
            for (int i = 0; i < 16; ++i) { float d = v[i] - mean; q = fmaf(d, d, q); }
            q += __shfl_xor(q, 16, 64);
            q += __shfl_xor(q, 32, 64);
            float rstd = rsqrtf(q * 0.015625f + LN_EPS);
#pragma unroll
            for (int dt = 0; dt < 4; ++dt)
#pragma unroll
                for (int r = 0; r < 4; ++r) {
                    int ch = dt * 16 + quad * 4 + r;
                    vln[pt][dt * 4 + r] = (v[dt * 4 + r] - mean) * rstd * lng[ch] + lnb[ch];
                }
        }
        __syncthreads();                     // all tile reads done; reuse TE
        ushort* OutT = &TE[0][0];            // [128][72]
#pragma unroll
        for (int pt = 0; pt < 2; ++pt) {
            const int m = m0 + pt * 16 + l15;
#pragma unroll
            for (int dt = 0; dt < 4; ++dt) {
                bf16x4 pk;
                pk[0] = (short)f2bf(vln[pt][dt * 4 + 0]);
                pk[1] = (short)f2bf(vln[pt][dt * 4 + 1]);
                pk[2] = (short)f2bf(vln[pt][dt * 4 + 2]);
                pk[3] = (short)f2bf(vln[pt][dt * 4 + 3]);
                *(bf16x4*)&OutT[m * 72 + dt * 16 + quad * 4] = pk;
            }
        }
        __syncthreads();
        for (int idx = tid; idx < 1024; idx += 256) {
            int row = idx >> 3, chb = (idx & 7) * 8;
            *(bf16x8*)(hout + ((size_t)b * LOUT + l0 + row) * 64 + chb) =
                *(const bf16x8*)&OutT[row * 72 + chb];
        }
    } else {
#pragma unroll
        for (int pt = 0; pt < 2; ++pt) {
            const int l = l0 + m0 + pt * 16 + l15;
            float* ob = out + ((size_t)(b * 512) + l) * 64;
#pragma unroll
            for (int dt = 0; dt < 4; ++dt) {
                float4 st = make_float4(fast_tanh(acc[pt][dt][0] + cb[dt * 16 + quad * 4 + 0]),
                                        fast_tanh(acc[pt][dt][1] + cb[dt * 16 + quad * 4 + 1]),
                                        fast_tanh(acc[pt][dt][2] + cb[dt * 16 + quad * 4 + 2]),
                                        fast_tanh(acc[pt][dt][3] + cb[dt * 16 + quad * 4 + 3]));
                *(float4*)(ob + dt * 16 + quad * 4) = st;
            }
        }
    }
}

extern "C" void kernel_launch(void* const* d_in, const int* in_sizes, int n_in,
                              void* d_out, int out_size, void* d_ws, size_t ws_size,
                              hipStream_t stream) {
    (void)in_sizes; (void)n_in; (void)out_size; (void)ws_size;
    const float* x   = (const float*)d_in[0];
    const float* w3  = (const float*)d_in[1];
    const float* b3  = (const float*)d_in[2];
    const float* w5  = (const float*)d_in[3];
    const float* b5  = (const float*)d_in[4];
    const float* w7  = (const float*)d_in[5];
    const float* b7  = (const float*)d_in[6];
    const float* w9  = (const float*)d_in[7];
    const float* b9  = (const float*)d_in[8];
    const float* cw1 = (const float*)d_in[9];
    const float* cb1 = (const float*)d_in[10];
    const float* cw2 = (const float*)d_in[11];
    const float* cb2 = (const float*)d_in[12];
    const float* cw3 = (const float*)d_in[13];
    const float* cb3 = (const float*)d_in[14];
    const float* lg1 = (const float*)d_in[15];
    const float* lb1 = (const float*)d_in[16];
    const float* lg2 = (const float*)d_in[17];
    const float* lb2 = (const float*)d_in[18];
    float* out = (float*)d_out;

    // ws layout (bytes):
    char* w = (char*)d_ws;
    ushort* Wm   = (ushort*)(w + 0);          //  98304 B (3 x 16384 bf16)
    float*  w9p  = (float*)(w + 98304);       //   2304 B
    float*  tb   = (float*)(w + 100608);      //    256 B
    float*  pe1c = (float*)(w + 100864);      // 524288 B (2048 x 64 fp32)
    ushort* h1   = (ushort*)(w + 625152);     // 33554432 B (128,2048,64) bf16
    ushort* h2   = (ushort*)(w + 34179584);   // 16777216 B (128,1024,64) bf16

    prep_kernel<<<192, 256, 0, stream>>>(cw1, cw2, cw3, w3, b3, w5, b5, w7, b7, w9, b9,
                                         Wm, w9p, tb);
    pe1_kernel<<<32, 256, 0, stream>>>(cw1, cb1, pe1c);

    stage_mfma<1><<<dim3(16, BATCH), 256, 0, stream>>>(
        x, nullptr, Wm, w9p, tb, pe1c, nullptr, lg1, lb1, h1, nullptr);
    stage_mfma<2><<<dim3(8, BATCH), 256, 0, stream>>>(
        nullptr, h1, Wm + 16384, nullptr, nullptr, nullptr, cb2, lg2, lb2, h2, nullptr);
    stage_mfma<3><<<dim3(4, BATCH), 256, 0, stream>>>(
        nullptr, h2, Wm + 32768, nullptr, nullptr, nullptr, cb3, nullptr, nullptr, nullptr, out);
}